// Round 3
// baseline (3568.012 us; speedup 1.0000x reference)
//
#include <hip/hip_runtime.h>

// RecurrentNEFLayer on MI355X — persistent-kernel scan.
// 128 blocks = 8 batch-groups (32 rows) x 16 neuron-groups (128 neurons).
// Weights LDS-resident (bf16) for all 512 steps; per-step 16-block group barrier
// reduces s_{t+1} via agent-scope f32 atomics into rotating global buffers.
// r3 changes: NO cooperative launch (plain launch, 128 blocks <= 256 CUs ensures
// co-residency), seq prefetch into registers, tighter spin cap.

constexpr int CB   = 256;   // batch
constexpr int CT   = 512;   // time steps
constexpr int DIN  = 128;
constexpr int DST  = 128;
constexpr int DOUT = 64;
constexpr int DAUG = 256;   // DIN + DST

constexpr int NBG = 8;      // batch groups
constexpr int NNG = 16;     // neuron groups (blocks per barrier group)
constexpr int BT  = 32;     // batch rows per group
constexpr int NT  = 128;    // neurons per block

constexpr int EPAD = 264;   // 256 + 8 bf16 pad (row stride ≡ 4 dwords mod 32 → 2-way, free)
constexpr int APAD = 136;   // 128 + 8 bf16 pad

using f32x4  = __attribute__((ext_vector_type(4))) float;
using bf16x8 = __attribute__((ext_vector_type(8))) short;   // 8 bf16 in 4 VGPRs

__device__ __forceinline__ short f2b(float x) {   // f32 -> bf16 RNE
  unsigned u = __builtin_bit_cast(unsigned, x);
  u += 0x7fffu + ((u >> 16) & 1u);
  return (short)(u >> 16);
}
__device__ __forceinline__ short4 f2b4(float4 v) {
  return make_short4(f2b(v.x), f2b(v.y), f2b(v.z), f2b(v.w));
}

// 16-block group barrier: monotonic counter, release/acquire via __threadfence
// (emits buffer_wbl2 / buffer_inv at agent scope — covers cross-XCD L2).
// Spin is capped: if co-residency were ever violated we produce a wrong answer
// in bounded time (~2 ms/barrier worst) instead of wedging the device.
__device__ __forceinline__ void group_barrier(unsigned int* ctr, unsigned int target) {
  __syncthreads();
  if (threadIdx.x == 0) {
    __threadfence();          // release: flush partial-sum atomics + zero-stores
    atomicAdd(ctr, 1u);
    unsigned int guard = 0;
    while (__hip_atomic_load(ctr, __ATOMIC_RELAXED, __HIP_MEMORY_SCOPE_AGENT) < target) {
      __builtin_amdgcn_s_sleep(1);
      if (++guard > 50000u) break;
    }
    __threadfence();          // acquire: invalidate L1/L2 before reading partials
  }
  __syncthreads();
}

__global__ void nef_init(float* S, unsigned int* ctrs, float* out) {
  int idx = blockIdx.x * blockDim.x + threadIdx.x;
  int stride = gridDim.x * blockDim.x;
  for (int i = idx; i < 4 * CB * DST; i += stride) S[i] = 0.f;   // 4 state buffers
  for (int i = idx; i < CB * DOUT; i += stride) out[i] = 0.f;
  if (idx < 16 * 64) ctrs[idx] = 0u;                             // barrier counters
}

__global__ void __launch_bounds__(256) nef_main(
    const float* __restrict__ seq,  const float* __restrict__ enc,
    const float* __restrict__ gainp,const float* __restrict__ biasp,
    const float* __restrict__ sdec, const float* __restrict__ dec,
    float* __restrict__ out, float* Sbuf, unsigned int* ctrs)
{
  __shared__ short E_lds[NT][EPAD];     // encoders tile  [n][k_aug]   67.6 KB
  __shared__ short SDT_lds[DST][APAD];  // state_dec^T    [d][n]       34.8 KB
  __shared__ short X_lds[BT][EPAD];     // [u_t | s_t]    [b][k_aug]   16.9 KB
  __shared__ short A_lds[BT][APAD];     // activations    [b][n]        8.7 KB
  __shared__ float gain_lds[NT];
  __shared__ float bias_lds[NT];

  const int tid  = threadIdx.x;
  const int bg   = blockIdx.x & 7;    // group's 16 blocks share an XCD (blockIdx%8 heuristic)
  const int ng   = blockIdx.x >> 3;
  const int b0   = bg * BT;
  const int n0   = ng * NT;
  const int wave = tid >> 6;
  const int lane = tid & 63;
  const int l15  = lane & 15;
  const int lhi  = lane >> 4;         // 0..3
  const int kbase = lhi * 8;

  // ---- one-time: stage weights into LDS (bf16) ----
  for (int i = 0; i < 32; ++i) {                       // encoders: 128x256 f32
    int fidx = i * 256 + tid;
    int row = fidx >> 6, c4 = fidx & 63;
    const float4 v = *(const float4*)(enc + (size_t)(n0 + row) * DAUG + (c4 << 2));
    *(short4*)&E_lds[row][c4 << 2] = f2b4(v);
  }
  for (int i = 0; i < 16; ++i) {                       // state_decoders: transpose
    int fidx = i * 256 + tid;
    int n = fidx >> 5, c4 = fidx & 31;
    const float4 v = *(const float4*)(sdec + (size_t)(n0 + n) * DST + (c4 << 2));
    SDT_lds[(c4 << 2) + 0][n] = f2b(v.x);
    SDT_lds[(c4 << 2) + 1][n] = f2b(v.y);
    SDT_lds[(c4 << 2) + 2][n] = f2b(v.z);
    SDT_lds[(c4 << 2) + 3][n] = f2b(v.w);
  }
  if (tid < NT) { gain_lds[tid] = gainp[n0 + tid]; bias_lds[tid] = biasp[n0 + tid]; }

  unsigned int* ctr = ctrs + bg * 64;   // one 256B-strided counter per group
  const int nsub0 = wave * 32, nsub1 = nsub0 + 16;   // this wave's two 16-col tiles

  // seq prefetch: 4 float4 per thread per step (32 rows x 32 float4-cols)
  float4 pu[4];
#pragma unroll
  for (int i = 0; i < 4; ++i) {
    int fidx = i * 256 + tid;
    int row = fidx >> 5, c4 = fidx & 31;
    pu[i] = *(const float4*)(seq + ((size_t)(b0 + row) * CT + 0) * DIN + (c4 << 2));
  }

  for (int t = 0; t < CT; ++t) {
    // rotate-zero S[(t+3)&3]: that buffer was read at t-1 (barrier'd), next
    // written at t+2 (two barriers later) -> safe. 16 blocks x 256 thr = 4096.
    float* Sz = Sbuf + ((t + 3) & 3) * (CB * DST);
    Sz[b0 * DST + ng * 256 + tid] = 0.f;

    // ---- stage x_aug = [u_t | s_t] into LDS as bf16 ----
    const float* Sr = Sbuf + (t & 3) * (CB * DST);
#pragma unroll
    for (int i = 0; i < 4; ++i) {
      int fidx = i * 256 + tid;
      int row = fidx >> 5, c4 = fidx & 31;
      *(short4*)&X_lds[row][c4 << 2] = f2b4(pu[i]);
      float4 w = *(const float4*)(Sr + (size_t)(b0 + row) * DST + (c4 << 2));
      *(short4*)&X_lds[row][DIN + (c4 << 2)] = f2b4(w);
    }
    if (t + 1 < CT) {   // prefetch u_{t+1}; latency hides under GEMMs + barrier
#pragma unroll
      for (int i = 0; i < 4; ++i) {
        int fidx = i * 256 + tid;
        int row = fidx >> 5, c4 = fidx & 31;
        pu[i] = *(const float4*)(seq + ((size_t)(b0 + row) * CT + (t + 1)) * DIN + (c4 << 2));
      }
    }
    __syncthreads();   // also covers one-time weight staging at t=0

    // ---- GEMM A: (32 x 256) @ (256 x 128) -> a; wave: 2 m-tiles x 2 n-tiles ----
    f32x4 acc00 = {0,0,0,0}, acc01 = {0,0,0,0}, acc10 = {0,0,0,0}, acc11 = {0,0,0,0};
#pragma unroll
    for (int kk = 0; kk < 8; ++kk) {
      bf16x8 a0 = *(const bf16x8*)&X_lds[l15][kk * 32 + kbase];
      bf16x8 a1 = *(const bf16x8*)&X_lds[16 + l15][kk * 32 + kbase];
      bf16x8 e0 = *(const bf16x8*)&E_lds[nsub0 + l15][kk * 32 + kbase];
      bf16x8 e1 = *(const bf16x8*)&E_lds[nsub1 + l15][kk * 32 + kbase];
      acc00 = __builtin_amdgcn_mfma_f32_16x16x32_bf16(a0, e0, acc00, 0, 0, 0);
      acc01 = __builtin_amdgcn_mfma_f32_16x16x32_bf16(a0, e1, acc01, 0, 0, 0);
      acc10 = __builtin_amdgcn_mfma_f32_16x16x32_bf16(a1, e0, acc10, 0, 0, 0);
      acc11 = __builtin_amdgcn_mfma_f32_16x16x32_bf16(a1, e1, acc11, 0, 0, 0);
    }
    {   // epilogue: relu(gain*x + bias) -> bf16 a-tile in LDS
      const int nc0 = nsub0 + l15, nc1 = nsub1 + l15;
      const float g0 = gain_lds[nc0], bi0 = bias_lds[nc0];
      const float g1 = gain_lds[nc1], bi1 = bias_lds[nc1];
#pragma unroll
      for (int j = 0; j < 4; ++j) {   // C/D: col=lane&15, row=(lane>>4)*4+j (m89/m91)
        A_lds[lhi * 4 + j][nc0]      = f2b(fmaxf(g0 * acc00[j] + bi0, 0.f));
        A_lds[lhi * 4 + j][nc1]      = f2b(fmaxf(g1 * acc01[j] + bi1, 0.f));
        A_lds[16 + lhi * 4 + j][nc0] = f2b(fmaxf(g0 * acc10[j] + bi0, 0.f));
        A_lds[16 + lhi * 4 + j][nc1] = f2b(fmaxf(g1 * acc11[j] + bi1, 0.f));
      }
    }
    __syncthreads();

    if (t != CT - 1) {
      // ---- GEMM B: (32 x 128) @ (128 x 128) -> partial s_{t+1} ----
      f32x4 b00 = {0,0,0,0}, b01 = {0,0,0,0}, b10 = {0,0,0,0}, b11 = {0,0,0,0};
      const int d0 = nsub0 + l15, d1 = nsub1 + l15;
#pragma unroll
      for (int kk = 0; kk < 4; ++kk) {
        bf16x8 a0 = *(const bf16x8*)&A_lds[l15][kk * 32 + kbase];
        bf16x8 a1 = *(const bf16x8*)&A_lds[16 + l15][kk * 32 + kbase];
        bf16x8 s0 = *(const bf16x8*)&SDT_lds[d0][kk * 32 + kbase];
        bf16x8 s1 = *(const bf16x8*)&SDT_lds[d1][kk * 32 + kbase];
        b00 = __builtin_amdgcn_mfma_f32_16x16x32_bf16(a0, s0, b00, 0, 0, 0);
        b01 = __builtin_amdgcn_mfma_f32_16x16x32_bf16(a0, s1, b01, 0, 0, 0);
        b10 = __builtin_amdgcn_mfma_f32_16x16x32_bf16(a1, s0, b10, 0, 0, 0);
        b11 = __builtin_amdgcn_mfma_f32_16x16x32_bf16(a1, s1, b11, 0, 0, 0);
      }
      float* Sw = Sbuf + ((t + 1) & 3) * (CB * DST);
#pragma unroll
      for (int j = 0; j < 4; ++j) {
        atomicAdd(&Sw[(size_t)(b0 + lhi * 4 + j) * DST + d0], b00[j]);
        atomicAdd(&Sw[(size_t)(b0 + lhi * 4 + j) * DST + d1], b01[j]);
        atomicAdd(&Sw[(size_t)(b0 + 16 + lhi * 4 + j) * DST + d0], b10[j]);
        atomicAdd(&Sw[(size_t)(b0 + 16 + lhi * 4 + j) * DST + d1], b11[j]);
      }
      group_barrier(ctr, (unsigned)NNG * (unsigned)(t + 1));
    } else {
      // ---- final step: out partial = a_final @ decoders[n0:n0+128] ----
      f32x4 o0 = {0,0,0,0}, o1 = {0,0,0,0};
      const int ocol = wave * 16 + l15;   // 4 waves x 16 = DOUT
#pragma unroll
      for (int kk = 0; kk < 4; ++kk) {
        bf16x8 a0 = *(const bf16x8*)&A_lds[l15][kk * 32 + kbase];
        bf16x8 a1 = *(const bf16x8*)&A_lds[16 + l15][kk * 32 + kbase];
        bf16x8 bfD;
#pragma unroll
        for (int j = 0; j < 8; ++j)
          bfD[j] = f2b(dec[(size_t)(n0 + kk * 32 + kbase + j) * DOUT + ocol]);
        o0 = __builtin_amdgcn_mfma_f32_16x16x32_bf16(a0, bfD, o0, 0, 0, 0);
        o1 = __builtin_amdgcn_mfma_f32_16x16x32_bf16(a1, bfD, o1, 0, 0, 0);
      }
#pragma unroll
      for (int j = 0; j < 4; ++j) {
        atomicAdd(&out[(size_t)(b0 + lhi * 4 + j) * DOUT + ocol], o0[j]);
        atomicAdd(&out[(size_t)(b0 + 16 + lhi * 4 + j) * DOUT + ocol], o1[j]);
      }
    }
  }
}

extern "C" void kernel_launch(void* const* d_in, const int* in_sizes, int n_in,
                              void* d_out, int out_size, void* d_ws, size_t ws_size,
                              hipStream_t stream) {
  const float* seq   = (const float*)d_in[0];
  const float* enc   = (const float*)d_in[1];
  const float* gainp = (const float*)d_in[2];
  const float* biasp = (const float*)d_in[3];
  const float* sdec  = (const float*)d_in[4];
  const float* dec   = (const float*)d_in[5];
  float* out = (float*)d_out;

  float* Sbuf = (float*)d_ws;                                   // 4 * 256*128 f32 = 512 KB
  unsigned int* ctrs = (unsigned int*)((char*)d_ws + (size_t)4 * CB * DST * sizeof(float));

  nef_init<<<128, 256, 0, stream>>>(Sbuf, ctrs, out);
  nef_main<<<dim3(NBG * NNG), dim3(256), 0, stream>>>(seq, enc, gainp, biasp,
                                                      sdec, dec, out, Sbuf, ctrs);
}